// Round 1
// baseline (287.178 us; speedup 1.0000x reference)
//
#include <hip/hip_runtime.h>

// B=8, T=1024, D=512, H=8, dh=64. All GEMM dims are multiples of 128/32 -> no bounds checks.
// Strategy: bf16 MFMA everywhere (threshold 0.68 vs expected err ~0.05), flash attention,
// multi-kernel pipeline on one stream. ws usage ~56 MB with aliasing.

typedef __bf16 bf16x8 __attribute__((ext_vector_type(8)));
typedef float f32x4 __attribute__((ext_vector_type(4)));
typedef unsigned short u16x8 __attribute__((ext_vector_type(8)));
typedef unsigned short u16x4 __attribute__((ext_vector_type(4)));

#define MFMA_BF16(a, b, c) __builtin_amdgcn_mfma_f32_16x16x32_bf16((a), (b), (c), 0, 0, 0)
#define NEGBIG (-4294967295.0f)

static __device__ __forceinline__ unsigned short f2bf(float f) {
    unsigned int u = __builtin_bit_cast(unsigned int, f);
    u += 0x7FFFu + ((u >> 16) & 1u);   // RNE
    return (unsigned short)(u >> 16);
}
static __device__ __forceinline__ float bf2f(unsigned short h) {
    return __builtin_bit_cast(float, ((unsigned int)h) << 16);
}

// ---------------- prep: q_in = queries + pos*sqrt(512), k_in = keys + pos*sqrt(512) (bf16) ----
__global__ __launch_bounds__(256) void prep_kernel(
    const float* __restrict__ q, const float* __restrict__ k,
    const float* __restrict__ pos,
    unsigned short* __restrict__ qo, unsigned short* __restrict__ ko)
{
    size_t i = ((size_t)blockIdx.x * 256 + threadIdx.x) * 4;
    size_t td = i & (size_t)(1024 * 512 - 1);          // index into (T,D) pos table
    float4 qv = *(const float4*)(q + i);
    float4 kv = *(const float4*)(k + i);
    float4 pv = *(const float4*)(pos + td);
    const float S = 22.627416997969522f;               // sqrt(512)
    u16x4 qr, kr;
    qr[0] = f2bf(qv.x + pv.x * S); qr[1] = f2bf(qv.y + pv.y * S);
    qr[2] = f2bf(qv.z + pv.z * S); qr[3] = f2bf(qv.w + pv.w * S);
    kr[0] = f2bf(kv.x + pv.x * S); kr[1] = f2bf(kv.y + pv.y * S);
    kr[2] = f2bf(kv.z + pv.z * S); kr[3] = f2bf(kv.w + pv.w * S);
    *(u16x4*)(qo + i) = qr;
    *(u16x4*)(ko + i) = kr;
}

// ---------------- weight transpose + bf16 cast: out[n][k] = bf16(in[k][n]) ------------------
__global__ __launch_bounds__(256) void wconv_kernel(
    const float* __restrict__ w0, const float* __restrict__ w1, const float* __restrict__ w2,
    const float* __restrict__ w3, const float* __restrict__ w4,
    unsigned short* __restrict__ o0, unsigned short* __restrict__ o1, unsigned short* __restrict__ o2,
    unsigned short* __restrict__ o3, unsigned short* __restrict__ o4)
{
    const float* in; unsigned short* out; int K, N;
    switch (blockIdx.z) {
        case 0: in = w0; out = o0; K = 512;  N = 512;  break;
        case 1: in = w1; out = o1; K = 512;  N = 512;  break;
        case 2: in = w2; out = o2; K = 512;  N = 512;  break;
        case 3: in = w3; out = o3; K = 512;  N = 2048; break;
        default: in = w4; out = o4; K = 2048; N = 512; break;
    }
    int k0 = blockIdx.x * 32, n0 = blockIdx.y * 32;
    if (k0 >= K || n0 >= N) return;
    __shared__ float tile[32][33];
    int tx = threadIdx.x & 31, ty = threadIdx.x >> 5;
#pragma unroll
    for (int i = 0; i < 32; i += 8)
        tile[ty + i][tx] = in[(size_t)(k0 + ty + i) * N + n0 + tx];
    __syncthreads();
#pragma unroll
    for (int i = 0; i < 32; i += 8)
        out[(size_t)(n0 + ty + i) * K + k0 + tx] = f2bf(tile[tx][ty + i]);
}

// ---------------- GEMM: C(MxN) = A(MxK) * B(KxN), B supplied transposed (Bt: NxK) -----------
// 128x128 tile, 4 waves (2x2 of 64x64), BK=32, LDS pad 40 (2-way conflicts only).
__global__ __launch_bounds__(256, 2) void gemm_bt(
    const unsigned short* __restrict__ A,
    const unsigned short* __restrict__ Bt,
    unsigned short* __restrict__ C,
    int M, int N, int K, int do_relu)
{
    __shared__ unsigned short As[128 * 40];
    __shared__ unsigned short Bs[128 * 40];
    const int tid = threadIdx.x;
    const int wave = tid >> 6, lane = tid & 63;
    const int g = lane >> 4, lr = lane & 15;
    const int wm = (wave >> 1) * 64, wn = (wave & 1) * 64;
    const size_t bm = (size_t)blockIdx.x * 128, bn = (size_t)blockIdx.y * 128;

    const int arow = tid >> 2, akk = (tid & 3) * 8;    // 512 chunks of 8 bf16, 2 per thread
    const unsigned short* Ap = A + (bm + arow) * (size_t)K + akk;
    const unsigned short* Bp = Bt + (bn + arow) * (size_t)K + akk;
    unsigned short* AsW = &As[arow * 40 + akk];
    unsigned short* BsW = &Bs[arow * 40 + akk];

    f32x4 acc[4][4];
#pragma unroll
    for (int i = 0; i < 4; ++i)
#pragma unroll
        for (int j = 0; j < 4; ++j) acc[i][j] = (f32x4){0.f, 0.f, 0.f, 0.f};

    for (int k0 = 0; k0 < K; k0 += 32) {
        u16x8 a0 = *(const u16x8*)(Ap + k0);
        u16x8 a1 = *(const u16x8*)(Ap + (size_t)64 * K + k0);
        u16x8 b0 = *(const u16x8*)(Bp + k0);
        u16x8 b1 = *(const u16x8*)(Bp + (size_t)64 * K + k0);
        __syncthreads();
        *(u16x8*)AsW = a0;
        *(u16x8*)(AsW + 64 * 40) = a1;
        *(u16x8*)BsW = b0;
        *(u16x8*)(BsW + 64 * 40) = b1;
        __syncthreads();
        bf16x8 af[4], bfr[4];
#pragma unroll
        for (int t = 0; t < 4; ++t) {
            af[t]  = *(const bf16x8*)&As[(wm + t * 16 + lr) * 40 + g * 8];
            bfr[t] = *(const bf16x8*)&Bs[(wn + t * 16 + lr) * 40 + g * 8];
        }
#pragma unroll
        for (int rt = 0; rt < 4; ++rt)
#pragma unroll
            for (int ct = 0; ct < 4; ++ct)
                acc[rt][ct] = MFMA_BF16(af[rt], bfr[ct], acc[rt][ct]);
    }

#pragma unroll
    for (int rt = 0; rt < 4; ++rt)
#pragma unroll
        for (int ct = 0; ct < 4; ++ct) {
            size_t row = bm + wm + rt * 16 + g * 4;   // C-layout: row=4g+reg, col=lr
            size_t col = bn + wn + ct * 16 + lr;
#pragma unroll
            for (int r = 0; r < 4; ++r) {
                float x = acc[rt][ct][r];
                if (do_relu) x = fmaxf(x, 0.f);
                C[(row + r) * (size_t)N + col] = f2bf(x);
            }
        }
}

// ---------------- flash attention + residual -------------------------------------------------
// grid (T/64, B*H); block 256 = 4 waves, each wave owns 16 q-rows. K/V tiles of 64 keys in LDS.
__global__ __launch_bounds__(256, 2) void attn_kernel(
    const unsigned short* __restrict__ Q,
    const unsigned short* __restrict__ Kp,
    const unsigned short* __restrict__ V,
    const float* __restrict__ queries,
    const float* __restrict__ pos,
    const float* __restrict__ kmask,
    const float* __restrict__ qmask,
    unsigned short* __restrict__ Res)
{
    __shared__ unsigned short Ks[64 * 72];     // [key][d]
    __shared__ unsigned short Vts[64 * 72];    // [d][key]  (transposed for PV B-frags)
    __shared__ unsigned short Ps[4][16 * 72];  // per-wave P round-trip (C-layout -> A-layout)
    const int tid = threadIdx.x, wave = tid >> 6, lane = tid & 63;
    const int g = lane >> 4, lr = lane & 15;
    const int b = blockIdx.y >> 3, h = blockIdx.y & 7;
    const int qrow = blockIdx.x * 64 + wave * 16;

    bf16x8 aq[2];
    {
        const unsigned short* qp = Q + ((size_t)(b * 1024 + qrow + lr)) * 512 + h * 64 + g * 8;
        aq[0] = *(const bf16x8*)qp;
        aq[1] = *(const bf16x8*)(qp + 32);
    }

    float m_run[4], l_run[4];
    f32x4 o[4];
#pragma unroll
    for (int i = 0; i < 4; ++i) { m_run[i] = -3.0e38f; l_run[i] = 0.f; o[i] = (f32x4){0.f,0.f,0.f,0.f}; }

    const int skey = tid >> 2, sd = (tid & 3) * 16;
    const size_t stage_base = ((size_t)(b * 1024)) * 512 + h * 64 + sd;

    for (int j0 = 0; j0 < 1024; j0 += 64) {
        const unsigned short* kp = Kp + stage_base + (size_t)(j0 + skey) * 512;
        const unsigned short* vp = V  + stage_base + (size_t)(j0 + skey) * 512;
        u16x8 k0v = *(const u16x8*)kp;
        u16x8 k1v = *(const u16x8*)(kp + 8);
        u16x8 v0v = *(const u16x8*)vp;
        u16x8 v1v = *(const u16x8*)(vp + 8);
        __syncthreads();                       // prior iteration's reads done
        *(u16x8*)&Ks[skey * 72 + sd] = k0v;
        *(u16x8*)&Ks[skey * 72 + sd + 8] = k1v;
#pragma unroll
        for (int i = 0; i < 8; ++i) Vts[(sd + i) * 72 + skey] = v0v[i];
#pragma unroll
        for (int i = 0; i < 8; ++i) Vts[(sd + 8 + i) * 72 + skey] = v1v[i];
        __syncthreads();

        // S = Q K^T (16 q-rows x 64 keys per wave)
        f32x4 s[4];
#pragma unroll
        for (int ct = 0; ct < 4; ++ct) {
            bf16x8 bk0 = *(const bf16x8*)&Ks[(ct * 16 + lr) * 72 + g * 8];
            bf16x8 bk1 = *(const bf16x8*)&Ks[(ct * 16 + lr) * 72 + 32 + g * 8];
            f32x4 z = (f32x4){0.f, 0.f, 0.f, 0.f};
            z = MFMA_BF16(aq[0], bk0, z);
            s[ct] = MFMA_BF16(aq[1], bk1, z);
        }

        // scale, key-mask, diagonal blinding; row max
        float rmax[4] = {-3.0e38f, -3.0e38f, -3.0e38f, -3.0e38f};
#pragma unroll
        for (int ct = 0; ct < 4; ++ct) {
            int kc = j0 + ct * 16 + lr;
            float km = kmask[b * 1024 + kc];
#pragma unroll
            for (int r = 0; r < 4; ++r) {
                int qr = qrow + g * 4 + r;
                float x = s[ct][r] * 0.125f;
                x = (km == 1.0f) ? x : NEGBIG;
                x = (qr == kc) ? NEGBIG : x;
                s[ct][r] = x;
                rmax[r] = fmaxf(rmax[r], x);
            }
        }
#pragma unroll
        for (int m = 1; m < 16; m <<= 1)
#pragma unroll
            for (int r = 0; r < 4; ++r)
                rmax[r] = fmaxf(rmax[r], __shfl_xor(rmax[r], m, 64));

        float alpha[4], psum[4];
#pragma unroll
        for (int r = 0; r < 4; ++r) {
            float mn = fmaxf(m_run[r], rmax[r]);
            alpha[r] = __expf(m_run[r] - mn);
            m_run[r] = mn;
            psum[r] = 0.f;
        }
#pragma unroll
        for (int ct = 0; ct < 4; ++ct)
#pragma unroll
            for (int r = 0; r < 4; ++r) {
                float p = __expf(s[ct][r] - m_run[r]);
                psum[r] += p;
                Ps[wave][(g * 4 + r) * 72 + ct * 16 + lr] = f2bf(p);
            }
#pragma unroll
        for (int m = 1; m < 16; m <<= 1)
#pragma unroll
            for (int r = 0; r < 4; ++r)
                psum[r] += __shfl_xor(psum[r], m, 64);
#pragma unroll
        for (int r = 0; r < 4; ++r) l_run[r] = l_run[r] * alpha[r] + psum[r];
#pragma unroll
        for (int ct = 0; ct < 4; ++ct)
#pragma unroll
            for (int r = 0; r < 4; ++r) o[ct][r] *= alpha[r];

        // O += P @ V  (per-wave Ps region: same-wave LDS dep, compiler inserts lgkmcnt wait)
        bf16x8 ap0 = *(const bf16x8*)&Ps[wave][lr * 72 + g * 8];
        bf16x8 ap1 = *(const bf16x8*)&Ps[wave][lr * 72 + 32 + g * 8];
#pragma unroll
        for (int ct = 0; ct < 4; ++ct) {
            bf16x8 bv0 = *(const bf16x8*)&Vts[(ct * 16 + lr) * 72 + g * 8];
            bf16x8 bv1 = *(const bf16x8*)&Vts[(ct * 16 + lr) * 72 + 32 + g * 8];
            o[ct] = MFMA_BF16(ap0, bv0, o[ct]);
            o[ct] = MFMA_BF16(ap1, bv1, o[ct]);
        }
    }

    // epilogue: normalize, query-mask, add residual q_in = queries + pos*sqrt(512)
#pragma unroll
    for (int ct = 0; ct < 4; ++ct)
#pragma unroll
        for (int r = 0; r < 4; ++r) {
            int t = qrow + g * 4 + r;
            int d = h * 64 + ct * 16 + lr;
            float qm = qmask[b * 1024 + t];
            float val = o[ct][r] / l_run[r] * qm;
            size_t idx = ((size_t)(b * 1024 + t)) * 512 + d;
            val += queries[idx] + pos[(size_t)t * 512 + d] * 22.627416997969522f;
            Res[idx] = f2bf(val);
        }
}

// ---------------- final: out[b,d] = mean_t(result + ffn) -------------------------------------
__global__ __launch_bounds__(512) void reduce_mean(
    const unsigned short* __restrict__ res,
    const unsigned short* __restrict__ ffn,
    float* __restrict__ out)
{
    const int b = blockIdx.x;
    const int t0 = blockIdx.y * 64;
    const int d = threadIdx.x;
    float acc = 0.f;
    for (int t = t0; t < t0 + 64; ++t) {
        size_t idx = ((size_t)(b * 1024 + t)) * 512 + d;
        acc += bf2f(res[idx]) + bf2f(ffn[idx]);
    }
    atomicAdd(out + b * 512 + d, acc * (1.0f / 1024.0f));
}

extern "C" void kernel_launch(void* const* d_in, const int* in_sizes, int n_in,
                              void* d_out, int out_size, void* d_ws, size_t ws_size,
                              hipStream_t stream)
{
    (void)in_sizes; (void)n_in; (void)out_size; (void)ws_size;
    const float* queries     = (const float*)d_in[0];
    const float* keys        = (const float*)d_in[1];
    const float* query_masks = (const float*)d_in[2];
    const float* key_masks   = (const float*)d_in[3];
    const float* pos_table   = (const float*)d_in[4];
    const float* W_Query     = (const float*)d_in[5];
    const float* W_key       = (const float*)d_in[6];
    const float* W_Value     = (const float*)d_in[7];
    const float* fw1         = (const float*)d_in[8];
    const float* fw2         = (const float*)d_in[9];
    float* out = (float*)d_out;

    unsigned short* ws = (unsigned short*)d_ws;
    const size_t NE = (size_t)8 * 1024 * 512;          // 4,194,304
    unsigned short* q_in   = ws;                        // later reused as `result`
    unsigned short* k_in   = ws + NE;                   // later reused as `ffn`
    unsigned short* qb     = ws + 2 * NE;               // `hidden` starts here (4*NE)
    unsigned short* kb     = ws + 3 * NE;
    unsigned short* vb     = ws + 4 * NE;
    unsigned short* result = q_in;
    unsigned short* hidden = qb;
    unsigned short* ffnb   = k_in;
    unsigned short* wqt    = ws + 6 * NE;
    unsigned short* wkt    = wqt + 512 * 512;
    unsigned short* wvt    = wkt + 512 * 512;
    unsigned short* fw1t   = wvt + 512 * 512;           // 2048 x 512
    unsigned short* fw2t   = fw1t + 2048 * 512;         // 512 x 2048
    // total ws: ~56 MB

    hipMemsetAsync(d_out, 0, 8 * 512 * sizeof(float), stream);
    prep_kernel<<<4096, 256, 0, stream>>>(queries, keys, pos_table, q_in, k_in);
    wconv_kernel<<<dim3(64, 64, 5), 256, 0, stream>>>(W_Query, W_key, W_Value, fw1, fw2,
                                                      wqt, wkt, wvt, fw1t, fw2t);
    gemm_bt<<<dim3(64, 4), 256, 0, stream>>>(q_in, wqt, qb, 8192, 512, 512, 0);
    gemm_bt<<<dim3(64, 4), 256, 0, stream>>>(k_in, wkt, kb, 8192, 512, 512, 0);
    gemm_bt<<<dim3(64, 4), 256, 0, stream>>>(kb, wvt, vb, 8192, 512, 512, 0);   // v from projected k
    attn_kernel<<<dim3(16, 64), 256, 0, stream>>>(qb, kb, vb, queries, pos_table,
                                                  key_masks, query_masks, result);
    gemm_bt<<<dim3(64, 16), 256, 0, stream>>>(result, fw1t, hidden, 8192, 2048, 512, 1);
    gemm_bt<<<dim3(64, 4), 256, 0, stream>>>(hidden, fw2t, ffnb, 8192, 512, 2048, 0);
    reduce_mean<<<dim3(8, 16), 512, 0, stream>>>(result, ffnb, out);
}

// Round 2
// 264.256 us; speedup vs baseline: 1.0867x; 1.0867x over previous
//
#include <hip/hip_runtime.h>

// B=8, T=1024, D=512, H=8, dh=64.
// bf16 MFMA pipeline: prep -> wconv -> Wkv^T (512^3) -> batched q/k/v proj ->
// flash attention (S^T orientation) -> ffn1(relu) -> ffn2 -> mean reduce.

typedef __bf16 bf16x8 __attribute__((ext_vector_type(8)));
typedef __bf16 bf16x4 __attribute__((ext_vector_type(4)));
typedef float f32x4 __attribute__((ext_vector_type(4)));
typedef unsigned short u16x8 __attribute__((ext_vector_type(8)));
typedef unsigned short u16x4 __attribute__((ext_vector_type(4)));

#define MFMA_BF16(a, b, c) __builtin_amdgcn_mfma_f32_16x16x32_bf16((a), (b), (c), 0, 0, 0)
#define NEGBIG (-4294967295.0f)

// async 16B/lane global->LDS. Dest is wave-uniform base + lane*16 (m104/m108).
#define GLL16(g, l)                                                                 \
    __builtin_amdgcn_global_load_lds((__attribute__((address_space(1))) void*)(g),  \
                                     (__attribute__((address_space(3))) void*)(l),  \
                                     16, 0, 0)

static __device__ __forceinline__ unsigned short f2bf(float f) {
    __bf16 h = (__bf16)f;                      // RNE, packs to v_cvt_pk_bf16_f32
    return __builtin_bit_cast(unsigned short, h);
}
static __device__ __forceinline__ float bf2f(unsigned short h) {
    return __builtin_bit_cast(float, ((unsigned int)h) << 16);
}

// ---------------- prep: q_in = queries + pos*sqrt(512), k_in = keys + pos*sqrt(512) ----------
__global__ __launch_bounds__(256) void prep_kernel(
    const float* __restrict__ q, const float* __restrict__ k,
    const float* __restrict__ pos,
    unsigned short* __restrict__ qo, unsigned short* __restrict__ ko)
{
    size_t i = ((size_t)blockIdx.x * 256 + threadIdx.x) * 4;
    size_t td = i & (size_t)(1024 * 512 - 1);
    float4 qv = *(const float4*)(q + i);
    float4 kv = *(const float4*)(k + i);
    float4 pv = *(const float4*)(pos + td);
    const float S = 22.627416997969522f;
    u16x4 qr, kr;
    qr[0] = f2bf(qv.x + pv.x * S); qr[1] = f2bf(qv.y + pv.y * S);
    qr[2] = f2bf(qv.z + pv.z * S); qr[3] = f2bf(qv.w + pv.w * S);
    kr[0] = f2bf(kv.x + pv.x * S); kr[1] = f2bf(kv.y + pv.y * S);
    kr[2] = f2bf(kv.z + pv.z * S); kr[3] = f2bf(kv.w + pv.w * S);
    *(u16x4*)(qo + i) = qr;
    *(u16x4*)(ko + i) = kr;
}

// ---------------- weight transpose + cast; also plain bf16 cast of W_key (z==1) --------------
__global__ __launch_bounds__(256) void wconv_kernel(
    const float* __restrict__ w0, const float* __restrict__ w1, const float* __restrict__ w2,
    const float* __restrict__ w3, const float* __restrict__ w4,
    unsigned short* __restrict__ o0, unsigned short* __restrict__ o1, unsigned short* __restrict__ o2,
    unsigned short* __restrict__ o3, unsigned short* __restrict__ o4,
    unsigned short* __restrict__ wkp)
{
    const float* in; unsigned short* out; int K, N;
    switch (blockIdx.z) {
        case 0: in = w0; out = o0; K = 512;  N = 512;  break;
        case 1: in = w1; out = o1; K = 512;  N = 512;  break;
        case 2: in = w2; out = o2; K = 512;  N = 512;  break;
        case 3: in = w3; out = o3; K = 512;  N = 2048; break;
        default: in = w4; out = o4; K = 2048; N = 512; break;
    }
    int k0 = blockIdx.x * 32, n0 = blockIdx.y * 32;
    if (k0 >= K || n0 >= N) return;
    __shared__ float tile[32][33];
    int tx = threadIdx.x & 31, ty = threadIdx.x >> 5;
#pragma unroll
    for (int i = 0; i < 32; i += 8) {
        float v = in[(size_t)(k0 + ty + i) * N + n0 + tx];
        tile[ty + i][tx] = v;
        if (blockIdx.z == 1) wkp[(size_t)(k0 + ty + i) * 512 + n0 + tx] = f2bf(v);
    }
    __syncthreads();
#pragma unroll
    for (int i = 0; i < 32; i += 8)
        out[(size_t)(n0 + ty + i) * K + k0 + tx] = f2bf(tile[tx][ty + i]);
}

// ---------------- GEMM core (m97 pattern): 128x128 tile, BK=32, global_load_lds width 16 -----
static __device__ __forceinline__ void gemm_core(
    const unsigned short* __restrict__ A,
    const unsigned short* __restrict__ Bt,
    unsigned short* __restrict__ C,
    int N, int K, int do_relu,
    unsigned short* As, unsigned short* Bs, int bx, int by)
{
    const int tid = threadIdx.x;
    const int wave = tid >> 6, lane = tid & 63;
    const int g = lane >> 4, lr = lane & 15;
    const int wm = (wave >> 1) * 64, wn = (wave & 1) * 64;
    const size_t bm = (size_t)bx * 128, bn = (size_t)by * 128;

    const int srow = tid >> 2, skc = (tid & 3) * 8;   // staging: 16B per lane
    const unsigned short* Ap = A + (bm + srow) * (size_t)K + skc;
    const unsigned short* Bp = Bt + (bn + srow) * (size_t)K + skc;
    unsigned short* AsW = As + tid * 8;               // lane-contiguous dest
    unsigned short* BsW = Bs + tid * 8;

    f32x4 acc[4][4] = {};

    for (int k0 = 0; k0 < K; k0 += 32) {
        __syncthreads();                               // LDS free from prev iter reads
        GLL16(Ap + k0, AsW);
        GLL16(Ap + (size_t)64 * K + k0, AsW + 2048);
        GLL16(Bp + k0, BsW);
        GLL16(Bp + (size_t)64 * K + k0, BsW + 2048);
        __syncthreads();                               // drains vmcnt -> data visible
        bf16x8 af[4], bfr[4];
#pragma unroll
        for (int t = 0; t < 4; ++t) {
            af[t]  = *(const bf16x8*)&As[(wm + t * 16 + lr) * 32 + g * 8];
            bfr[t] = *(const bf16x8*)&Bs[(wn + t * 16 + lr) * 32 + g * 8];
        }
#pragma unroll
        for (int rt = 0; rt < 4; ++rt)
#pragma unroll
            for (int ct = 0; ct < 4; ++ct)
                acc[rt][ct] = MFMA_BF16(af[rt], bfr[ct], acc[rt][ct]);
    }

#pragma unroll
    for (int rt = 0; rt < 4; ++rt)
#pragma unroll
        for (int ct = 0; ct < 4; ++ct) {
            size_t row = bm + wm + rt * 16 + g * 4;
            size_t col = bn + wn + ct * 16 + lr;
#pragma unroll
            for (int r = 0; r < 4; ++r) {
                float x = acc[rt][ct][r];
                if (do_relu) x = fmaxf(x, 0.f);
                C[(row + r) * (size_t)N + col] = f2bf(x);
            }
        }
}

__global__ __launch_bounds__(256, 2) void gemm_bt(
    const unsigned short* __restrict__ A, const unsigned short* __restrict__ Bt,
    unsigned short* __restrict__ C, int N, int K, int do_relu)
{
    __shared__ unsigned short As[128 * 32];
    __shared__ unsigned short Bs[128 * 32];
    gemm_core(A, Bt, C, N, K, do_relu, As, Bs, blockIdx.x, blockIdx.y);
}

// batched q/k/v projections (v = k_in * Wkv, Wkv precomputed -> no dependency on k-proj)
__global__ __launch_bounds__(256, 2) void proj3_kernel(
    const unsigned short* __restrict__ q_in, const unsigned short* __restrict__ k_in,
    const unsigned short* __restrict__ wqt, const unsigned short* __restrict__ wkt,
    const unsigned short* __restrict__ wkvt,
    unsigned short* __restrict__ qb, unsigned short* __restrict__ kb,
    unsigned short* __restrict__ vb)
{
    __shared__ unsigned short As[128 * 32];
    __shared__ unsigned short Bs[128 * 32];
    const unsigned short *A, *Bt; unsigned short* C;
    switch (blockIdx.z) {
        case 0:  A = q_in; Bt = wqt;  C = qb; break;
        case 1:  A = k_in; Bt = wkt;  C = kb; break;
        default: A = k_in; Bt = wkvt; C = vb; break;
    }
    gemm_core(A, Bt, C, 512, 512, 0, As, Bs, blockIdx.x, blockIdx.y);
}

// ---------------- flash attention, S^T orientation --------------------------------------------
// grid (T/64, B*H); 4 waves; wave computes S^T (64 keys x 16 q), q = lane lr.
__global__ __launch_bounds__(256, 2) void attn_kernel(
    const unsigned short* __restrict__ Q,
    const unsigned short* __restrict__ Kp,
    const unsigned short* __restrict__ V,
    const float* __restrict__ queries,
    const float* __restrict__ pos,
    const float* __restrict__ kmask,
    const float* __restrict__ qmask,
    unsigned short* __restrict__ Res)
{
    __shared__ unsigned short Ks[64 * 72];    // [key][d]
    __shared__ unsigned short Vts[64 * 72];   // [d][key]
    __shared__ unsigned short Ps[4][16 * 72]; // per-wave P^T as [q][key]
    const int tid = threadIdx.x, wave = tid >> 6, lane = tid & 63;
    const int g = lane >> 4, lr = lane & 15;
    const int b = blockIdx.y >> 3, h = blockIdx.y & 7;
    const int qg = blockIdx.x * 64 + wave * 16 + lr;   // this lane's global q row

    bf16x8 aq0, aq1;                                    // Q as B-frag (B[k=d][n=q])
    {
        const unsigned short* qp = Q + ((size_t)(b * 1024 + qg)) * 512 + h * 64 + g * 8;
        aq0 = *(const bf16x8*)qp;
        aq1 = *(const bf16x8*)(qp + 32);
    }
    const float qm = qmask[b * 1024 + qg];

    float m_run = -3.0e38f, l_run = 0.f;
    f32x4 o[4] = {};                                    // O^T: d = dt*16+4g+r, q = lr

    const int skey = tid >> 2, sd = (tid & 3) * 16;     // K staging map
    const int vd0 = (tid & 15) * 4, vk0 = (tid >> 4) * 4; // V staging map (4x4 blocks)
    const unsigned short* kbase = Kp + ((size_t)(b * 1024)) * 512 + h * 64;
    const unsigned short* vbase = V + ((size_t)(b * 1024)) * 512 + h * 64;

    u16x8 kr0, kr1; u16x4 vr[4];
    {
        const unsigned short* kp = kbase + (size_t)skey * 512 + sd;
        kr0 = *(const u16x8*)kp; kr1 = *(const u16x8*)(kp + 8);
        const unsigned short* vp = vbase + (size_t)vk0 * 512 + vd0;
#pragma unroll
        for (int j = 0; j < 4; ++j) vr[j] = *(const u16x4*)(vp + (size_t)j * 512);
    }

    for (int j0 = 0; j0 < 1024; j0 += 64) {
        __syncthreads();
        *(u16x8*)&Ks[skey * 72 + sd] = kr0;
        *(u16x8*)&Ks[skey * 72 + sd + 8] = kr1;
#pragma unroll
        for (int i = 0; i < 4; ++i) {
            u16x4 w = { vr[0][i], vr[1][i], vr[2][i], vr[3][i] };
            *(u16x4*)&Vts[(vd0 + i) * 72 + vk0] = w;
        }
        __syncthreads();
        if (j0 + 64 < 1024) {                            // register prefetch of next tile
            const unsigned short* kp = kbase + (size_t)(j0 + 64 + skey) * 512 + sd;
            kr0 = *(const u16x8*)kp; kr1 = *(const u16x8*)(kp + 8);
            const unsigned short* vp = vbase + (size_t)(j0 + 64 + vk0) * 512 + vd0;
#pragma unroll
            for (int j = 0; j < 4; ++j) vr[j] = *(const u16x4*)(vp + (size_t)j * 512);
        }

        // S^T = K Q^T : s[ct] rows = keys ct*16+4g+r, col = q = lr
        f32x4 s[4];
#pragma unroll
        for (int ct = 0; ct < 4; ++ct) {
            bf16x8 ka = *(const bf16x8*)&Ks[(ct * 16 + lr) * 72 + g * 8];
            bf16x8 kc = *(const bf16x8*)&Ks[(ct * 16 + lr) * 72 + 32 + g * 8];
            f32x4 z = {};
            z = MFMA_BF16(ka, aq0, z);
            s[ct] = MFMA_BF16(kc, aq1, z);
        }

        // scale + key-mask + blinding; keys are in-lane -> cheap reductions
        float rmax = -3.0e38f;
#pragma unroll
        for (int ct = 0; ct < 4; ++ct) {
            f32x4 km4 = *(const f32x4*)&kmask[b * 1024 + j0 + ct * 16 + g * 4];
#pragma unroll
            for (int r = 0; r < 4; ++r) {
                int key = j0 + ct * 16 + g * 4 + r;
                float x = s[ct][r] * 0.125f;
                x = (km4[r] == 1.0f) ? x : NEGBIG;
                x = (key == qg) ? NEGBIG : x;
                s[ct][r] = x;
                rmax = fmaxf(rmax, x);
            }
        }
        rmax = fmaxf(rmax, __shfl_xor(rmax, 16, 64));
        rmax = fmaxf(rmax, __shfl_xor(rmax, 32, 64));

        float mn = fmaxf(m_run, rmax);
        float alpha = __expf(m_run - mn);
        m_run = mn;
        float psum = 0.f;
#pragma unroll
        for (int ct = 0; ct < 4; ++ct) {
            f32x4 p;
#pragma unroll
            for (int r = 0; r < 4; ++r) { p[r] = __expf(s[ct][r] - mn); psum += p[r]; }
            bf16x4 pk = { (__bf16)p[0], (__bf16)p[1], (__bf16)p[2], (__bf16)p[3] };
            *(bf16x4*)&Ps[wave][lr * 72 + ct * 16 + g * 4] = pk;   // packed b64
        }
        psum += __shfl_xor(psum, 16, 64);
        psum += __shfl_xor(psum, 32, 64);
        l_run = l_run * alpha + psum;
#pragma unroll
        for (int dt = 0; dt < 4; ++dt) o[dt] *= alpha;

        // O^T += V^T P^T  (same-wave Ps write->read; in-order LDS per wave)
        bf16x8 p0 = *(const bf16x8*)&Ps[wave][lr * 72 + g * 8];
        bf16x8 p1 = *(const bf16x8*)&Ps[wave][lr * 72 + 32 + g * 8];
#pragma unroll
        for (int dt = 0; dt < 4; ++dt) {
            bf16x8 va = *(const bf16x8*)&Vts[(dt * 16 + lr) * 72 + g * 8];
            bf16x8 vc = *(const bf16x8*)&Vts[(dt * 16 + lr) * 72 + 32 + g * 8];
            o[dt] = MFMA_BF16(va, p0, o[dt]);
            o[dt] = MFMA_BF16(vc, p1, o[dt]);
        }
    }

    // epilogue: normalize, query-mask, residual; per-lane scalar l_run (q = lr)
    const float inv_l = 1.0f / l_run;
    const float S = 22.627416997969522f;
#pragma unroll
    for (int dt = 0; dt < 4; ++dt) {
        size_t col = (size_t)h * 64 + dt * 16 + g * 4;
        size_t idx = ((size_t)(b * 1024 + qg)) * 512 + col;
        f32x4 qv = *(const f32x4*)&queries[idx];
        f32x4 pv = *(const f32x4*)&pos[(size_t)qg * 512 + col];
        u16x4 wr;
#pragma unroll
        for (int r = 0; r < 4; ++r)
            wr[r] = f2bf(o[dt][r] * inv_l * qm + qv[r] + pv[r] * S);
        *(u16x4*)&Res[idx] = wr;
    }
}

// ---------------- final: out[b,d] = mean_t(result + ffn) -------------------------------------
__global__ __launch_bounds__(512) void reduce_mean(
    const unsigned short* __restrict__ res,
    const unsigned short* __restrict__ ffn,
    float* __restrict__ out)
{
    const int b = blockIdx.x;
    const int t0 = blockIdx.y * 64;
    const int d = threadIdx.x;
    float acc = 0.f;
    for (int t = t0; t < t0 + 64; ++t) {
        size_t idx = ((size_t)(b * 1024 + t)) * 512 + d;
        acc += bf2f(res[idx]) + bf2f(ffn[idx]);
    }
    atomicAdd(out + b * 512 + d, acc * (1.0f / 1024.0f));
}

extern "C" void kernel_launch(void* const* d_in, const int* in_sizes, int n_in,
                              void* d_out, int out_size, void* d_ws, size_t ws_size,
                              hipStream_t stream)
{
    (void)in_sizes; (void)n_in; (void)out_size; (void)ws_size;
    const float* queries     = (const float*)d_in[0];
    const float* keys        = (const float*)d_in[1];
    const float* query_masks = (const float*)d_in[2];
    const float* key_masks   = (const float*)d_in[3];
    const float* pos_table   = (const float*)d_in[4];
    const float* W_Query     = (const float*)d_in[5];
    const float* W_key       = (const float*)d_in[6];
    const float* W_Value     = (const float*)d_in[7];
    const float* fw1         = (const float*)d_in[8];
    const float* fw2         = (const float*)d_in[9];
    float* out = (float*)d_out;

    unsigned short* ws = (unsigned short*)d_ws;
    const size_t NE = (size_t)8 * 1024 * 512;
    unsigned short* q_in   = ws;               // -> result after attn
    unsigned short* k_in   = ws + NE;          // -> ffn output after ffn2
    unsigned short* qb     = ws + 2 * NE;      // hidden (4*NE) starts here after attn
    unsigned short* kb     = ws + 3 * NE;
    unsigned short* vb     = ws + 4 * NE;
    unsigned short* result = q_in;
    unsigned short* hidden = qb;
    unsigned short* ffnb   = k_in;
    unsigned short* wqt    = ws + 6 * NE;
    unsigned short* wkt    = wqt + 512 * 512;
    unsigned short* wvt    = wkt + 512 * 512;
    unsigned short* fw1t   = wvt + 512 * 512;     // 2048 x 512
    unsigned short* fw2t   = fw1t + 2048 * 512;   // 512 x 2048
    unsigned short* wkp    = fw2t + 2048 * 512;   // bf16(W_key), plain
    unsigned short* wkvt   = wkp + 512 * 512;     // (Wk*Wv)^T

    hipMemsetAsync(d_out, 0, 8 * 512 * sizeof(float), stream);
    prep_kernel<<<4096, 256, 0, stream>>>(queries, keys, pos_table, q_in, k_in);
    wconv_kernel<<<dim3(64, 64, 5), 256, 0, stream>>>(W_Query, W_key, W_Value, fw1, fw2,
                                                      wqt, wkt, wvt, fw1t, fw2t, wkp);
    // Wkv^T = Wv^T * Wk^T  (C[m][n] = sum_k wvt[m][k]*wkp[n][k] = Wkv[n][m])
    gemm_bt<<<dim3(4, 4), 256, 0, stream>>>(wvt, wkp, wkvt, 512, 512, 0);
    proj3_kernel<<<dim3(64, 4, 3), 256, 0, stream>>>(q_in, k_in, wqt, wkt, wkvt, qb, kb, vb);
    attn_kernel<<<dim3(16, 64), 256, 0, stream>>>(qb, kb, vb, queries, pos_table,
                                                  key_masks, query_masks, result);
    gemm_bt<<<dim3(64, 16), 256, 0, stream>>>(result, fw1t, hidden, 2048, 512, 1);
    gemm_bt<<<dim3(64, 4), 256, 0, stream>>>(hidden, fw2t, ffnb, 512, 2048, 0);
    reduce_mean<<<dim3(8, 16), 512, 0, stream>>>(result, ffnb, out);
}

// Round 3
// 228.629 us; speedup vs baseline: 1.2561x; 1.1558x over previous
//
#include <hip/hip_runtime.h>

// B=8, T=1024, D=512, H=8, dh=64.
// bf16 MFMA pipeline: prep -> wconv(1D exact grid) -> Wkv^T -> batched q/k/v proj ->
// flash attention (128q/block, 8 waves) -> result-mean -> ffn1(relu) -> ffn2 split-K fused mean.

typedef __bf16 bf16x8 __attribute__((ext_vector_type(8)));
typedef __bf16 bf16x4 __attribute__((ext_vector_type(4)));
typedef float f32x4 __attribute__((ext_vector_type(4)));
typedef unsigned short u16x8 __attribute__((ext_vector_type(8)));
typedef unsigned short u16x4 __attribute__((ext_vector_type(4)));

#define MFMA_BF16(a, b, c) __builtin_amdgcn_mfma_f32_16x16x32_bf16((a), (b), (c), 0, 0, 0)
#define NEGBIG (-4294967295.0f)

#define GLL16(g, l)                                                                 \
    __builtin_amdgcn_global_load_lds((__attribute__((address_space(1))) void*)(g),  \
                                     (__attribute__((address_space(3))) void*)(l),  \
                                     16, 0, 0)

static __device__ __forceinline__ unsigned short f2bf(float f) {
    __bf16 h = (__bf16)f;
    return __builtin_bit_cast(unsigned short, h);
}
static __device__ __forceinline__ float bf2f(unsigned short h) {
    return __builtin_bit_cast(float, ((unsigned int)h) << 16);
}

// ---------------- prep: q_in = queries + pos*sqrt(512), k_in = keys + pos*sqrt(512) ----------
__global__ __launch_bounds__(256) void prep_kernel(
    const float* __restrict__ q, const float* __restrict__ k,
    const float* __restrict__ pos,
    unsigned short* __restrict__ qo, unsigned short* __restrict__ ko)
{
    size_t i = ((size_t)blockIdx.x * 256 + threadIdx.x) * 4;
    size_t td = i & (size_t)(1024 * 512 - 1);
    float4 qv = *(const float4*)(q + i);
    float4 kv = *(const float4*)(k + i);
    float4 pv = *(const float4*)(pos + td);
    const float S = 22.627416997969522f;
    u16x4 qr, kr;
    qr[0] = f2bf(qv.x + pv.x * S); qr[1] = f2bf(qv.y + pv.y * S);
    qr[2] = f2bf(qv.z + pv.z * S); qr[3] = f2bf(qv.w + pv.w * S);
    kr[0] = f2bf(kv.x + pv.x * S); kr[1] = f2bf(kv.y + pv.y * S);
    kr[2] = f2bf(kv.z + pv.z * S); kr[3] = f2bf(kv.w + pv.w * S);
    *(u16x4*)(qo + i) = qr;
    *(u16x4*)(ko + i) = kr;
}

// ---------------- weight transpose + cast, exact 1D grid (2816 blocks) -----------------------
// segs: [0,256) wq, [256,512) wk(+plain copy), [512,768) wv, [768,1792) fw1, [1792,2816) fw2
__global__ __launch_bounds__(256) void wconv_kernel(
    const float* __restrict__ w0, const float* __restrict__ w1, const float* __restrict__ w2,
    const float* __restrict__ w3, const float* __restrict__ w4,
    unsigned short* __restrict__ o0, unsigned short* __restrict__ o1, unsigned short* __restrict__ o2,
    unsigned short* __restrict__ o3, unsigned short* __restrict__ o4,
    unsigned short* __restrict__ wkp)
{
    int id = blockIdx.x;
    const float* in; unsigned short* out; int K, N, kt, nt; bool dup = false;
    if (id < 768) {
        int m = id >> 8; id &= 255;
        in  = (m == 0) ? w0 : ((m == 1) ? w1 : w2);
        out = (m == 0) ? o0 : ((m == 1) ? o1 : o2);
        dup = (m == 1);
        K = 512; N = 512; kt = id >> 4; nt = id & 15;
    } else if (id < 1792) {
        id -= 768; in = w3; out = o3; K = 512; N = 2048; kt = id >> 6; nt = id & 63;
    } else {
        id -= 1792; in = w4; out = o4; K = 2048; N = 512; kt = id >> 4; nt = id & 15;
    }
    int k0 = kt * 32, n0 = nt * 32;
    __shared__ float tile[32][33];
    int tx = threadIdx.x & 31, ty = threadIdx.x >> 5;
#pragma unroll
    for (int i = 0; i < 32; i += 8) {
        float v = in[(size_t)(k0 + ty + i) * N + n0 + tx];
        tile[ty + i][tx] = v;
        if (dup) wkp[(size_t)(k0 + ty + i) * 512 + n0 + tx] = f2bf(v);
    }
    __syncthreads();
#pragma unroll
    for (int i = 0; i < 32; i += 8)
        out[(size_t)(n0 + ty + i) * K + k0 + tx] = f2bf(tile[tx][ty + i]);
}

// ---------------- GEMM core (m97 pattern): 128x128 tile, BK=32, global_load_lds width 16 -----
static __device__ __forceinline__ void gemm_core(
    const unsigned short* __restrict__ A,
    const unsigned short* __restrict__ Bt,
    unsigned short* __restrict__ C,
    int N, int K, int do_relu,
    unsigned short* As, unsigned short* Bs, int bx, int by)
{
    const int tid = threadIdx.x;
    const int wave = tid >> 6, lane = tid & 63;
    const int g = lane >> 4, lr = lane & 15;
    const int wm = (wave >> 1) * 64, wn = (wave & 1) * 64;
    const size_t bm = (size_t)bx * 128, bn = (size_t)by * 128;

    const int srow = tid >> 2, skc = (tid & 3) * 8;
    const unsigned short* Ap = A + (bm + srow) * (size_t)K + skc;
    const unsigned short* Bp = Bt + (bn + srow) * (size_t)K + skc;
    unsigned short* AsW = As + tid * 8;
    unsigned short* BsW = Bs + tid * 8;

    f32x4 acc[4][4] = {};

    for (int k0 = 0; k0 < K; k0 += 32) {
        __syncthreads();
        GLL16(Ap + k0, AsW);
        GLL16(Ap + (size_t)64 * K + k0, AsW + 2048);
        GLL16(Bp + k0, BsW);
        GLL16(Bp + (size_t)64 * K + k0, BsW + 2048);
        __syncthreads();
        bf16x8 af[4], bfr[4];
#pragma unroll
        for (int t = 0; t < 4; ++t) {
            af[t]  = *(const bf16x8*)&As[(wm + t * 16 + lr) * 32 + g * 8];
            bfr[t] = *(const bf16x8*)&Bs[(wn + t * 16 + lr) * 32 + g * 8];
        }
#pragma unroll
        for (int rt = 0; rt < 4; ++rt)
#pragma unroll
            for (int ct = 0; ct < 4; ++ct)
                acc[rt][ct] = MFMA_BF16(af[rt], bfr[ct], acc[rt][ct]);
    }

#pragma unroll
    for (int rt = 0; rt < 4; ++rt)
#pragma unroll
        for (int ct = 0; ct < 4; ++ct) {
            size_t row = bm + wm + rt * 16 + g * 4;
            size_t col = bn + wn + ct * 16 + lr;
#pragma unroll
            for (int r = 0; r < 4; ++r) {
                float x = acc[rt][ct][r];
                if (do_relu) x = fmaxf(x, 0.f);
                C[(row + r) * (size_t)N + col] = f2bf(x);
            }
        }
}

__global__ __launch_bounds__(256, 2) void gemm_bt(
    const unsigned short* __restrict__ A, const unsigned short* __restrict__ Bt,
    unsigned short* __restrict__ C, int N, int K, int do_relu)
{
    __shared__ unsigned short As[128 * 32];
    __shared__ unsigned short Bs[128 * 32];
    gemm_core(A, Bt, C, N, K, do_relu, As, Bs, blockIdx.x, blockIdx.y);
}

// batched q/k/v projections (v = k_in * Wkv, Wkv precomputed)
__global__ __launch_bounds__(256, 2) void proj3_kernel(
    const unsigned short* __restrict__ q_in, const unsigned short* __restrict__ k_in,
    const unsigned short* __restrict__ wqt, const unsigned short* __restrict__ wkt,
    const unsigned short* __restrict__ wkvt,
    unsigned short* __restrict__ qb, unsigned short* __restrict__ kb,
    unsigned short* __restrict__ vb)
{
    __shared__ unsigned short As[128 * 32];
    __shared__ unsigned short Bs[128 * 32];
    const unsigned short *A, *Bt; unsigned short* C;
    switch (blockIdx.z) {
        case 0:  A = q_in; Bt = wqt;  C = qb; break;
        case 1:  A = k_in; Bt = wkt;  C = kb; break;
        default: A = k_in; Bt = wkvt; C = vb; break;
    }
    gemm_core(A, Bt, C, 512, 512, 0, As, Bs, blockIdx.x, blockIdx.y);
}

// ---------------- ffn2 with split-K, fused mean: atomicAdd column sums into out --------------
// grid (64, 4, 4): (m-tile, n-tile, k-slice of 512). No C write at all.
__global__ __launch_bounds__(256, 2) void ffn2_meank(
    const unsigned short* __restrict__ A,    // hidden [8192][2048]
    const unsigned short* __restrict__ Bt,   // fw2t   [512][2048]
    float* __restrict__ out)                 // [8][512]
{
    __shared__ unsigned short As[128 * 32];
    __shared__ unsigned short Bs[128 * 32];
    const int tid = threadIdx.x;
    const int wave = tid >> 6, lane = tid & 63;
    const int g = lane >> 4, lr = lane & 15;
    const int wm = (wave >> 1) * 64, wn = (wave & 1) * 64;
    const size_t bm = (size_t)blockIdx.x * 128, bn = (size_t)blockIdx.y * 128;
    const int koff = blockIdx.z * 512;

    const int srow = tid >> 2, skc = (tid & 3) * 8;
    const unsigned short* Ap = A + (bm + srow) * (size_t)2048 + koff + skc;
    const unsigned short* Bp = Bt + (bn + srow) * (size_t)2048 + koff + skc;
    unsigned short* AsW = As + tid * 8;
    unsigned short* BsW = Bs + tid * 8;

    f32x4 acc[4][4] = {};
    for (int k0 = 0; k0 < 512; k0 += 32) {
        __syncthreads();
        GLL16(Ap + k0, AsW);
        GLL16(Ap + (size_t)64 * 2048 + k0, AsW + 2048);
        GLL16(Bp + k0, BsW);
        GLL16(Bp + (size_t)64 * 2048 + k0, BsW + 2048);
        __syncthreads();
        bf16x8 af[4], bfr[4];
#pragma unroll
        for (int t = 0; t < 4; ++t) {
            af[t]  = *(const bf16x8*)&As[(wm + t * 16 + lr) * 32 + g * 8];
            bfr[t] = *(const bf16x8*)&Bs[(wn + t * 16 + lr) * 32 + g * 8];
        }
#pragma unroll
        for (int rt = 0; rt < 4; ++rt)
#pragma unroll
            for (int ct = 0; ct < 4; ++ct)
                acc[rt][ct] = MFMA_BF16(af[rt], bfr[ct], acc[rt][ct]);
    }

    // column sums over this tile's 128 rows (one b: 1024 % 128 == 0)
    const int b = (int)(bm >> 10);
#pragma unroll
    for (int ct = 0; ct < 4; ++ct) {
        float s = 0.f;
#pragma unroll
        for (int rt = 0; rt < 4; ++rt)
#pragma unroll
            for (int r = 0; r < 4; ++r) s += acc[rt][ct][r];
        s += __shfl_xor(s, 16, 64);
        s += __shfl_xor(s, 32, 64);
        if (g == 0)
            atomicAdd(out + b * 512 + bn + wn + ct * 16 + lr, s * (1.0f / 1024.0f));
    }
}

// ---------------- flash attention, S^T orientation, 128 q / block (8 waves) ------------------
__global__ __launch_bounds__(512, 4) void attn_kernel(
    const unsigned short* __restrict__ Q,
    const unsigned short* __restrict__ Kp,
    const unsigned short* __restrict__ V,
    const float* __restrict__ queries,
    const float* __restrict__ pos,
    const float* __restrict__ kmask,
    const float* __restrict__ qmask,
    unsigned short* __restrict__ Res)
{
    __shared__ unsigned short Ks[64 * 72];    // [key][d]
    __shared__ unsigned short Vts[64 * 72];   // [d][key]
    __shared__ unsigned short Ps[8][16 * 72]; // per-wave P^T as [q][key]
    const int tid = threadIdx.x, wave = tid >> 6, lane = tid & 63;
    const int g = lane >> 4, lr = lane & 15;
    const int b = blockIdx.y >> 3, h = blockIdx.y & 7;
    const int qg = blockIdx.x * 128 + wave * 16 + lr;

    bf16x8 aq0, aq1;
    {
        const unsigned short* qp = Q + ((size_t)(b * 1024 + qg)) * 512 + h * 64 + g * 8;
        aq0 = *(const bf16x8*)qp;
        aq1 = *(const bf16x8*)(qp + 32);
    }
    const float qm = qmask[b * 1024 + qg];

    float m_run = -3.0e38f, l_run = 0.f;
    f32x4 o[4] = {};                           // O^T: d = dt*16+4g+r, q = lr

    const unsigned short* kbase = Kp + ((size_t)(b * 1024)) * 512 + h * 64;
    const unsigned short* vbase = V + ((size_t)(b * 1024)) * 512 + h * 64;

    const int half = tid >> 8;                        // 0: V stager, 1: K stager
    const int skey = (tid & 255) >> 2, sd = (tid & 3) * 16;     // K map
    const int vk0 = (tid & 15) * 4, vd0 = ((tid >> 4) & 15) * 4; // V map (key-major lanes)

    u16x8 kr0, kr1; u16x4 vr[4];
    if (half) {
        const unsigned short* kp = kbase + (size_t)skey * 512 + sd;
        kr0 = *(const u16x8*)kp; kr1 = *(const u16x8*)(kp + 8);
    } else {
        const unsigned short* vp = vbase + (size_t)vk0 * 512 + vd0;
#pragma unroll
        for (int j = 0; j < 4; ++j) vr[j] = *(const u16x4*)(vp + (size_t)j * 512);
    }

    for (int j0 = 0; j0 < 1024; j0 += 64) {
        __syncthreads();
        if (half) {
            *(u16x8*)&Ks[skey * 72 + sd] = kr0;
            *(u16x8*)&Ks[skey * 72 + sd + 8] = kr1;
        } else {
#pragma unroll
            for (int i = 0; i < 4; ++i) {
                u16x4 w = { vr[0][i], vr[1][i], vr[2][i], vr[3][i] };
                *(u16x4*)&Vts[(vd0 + i) * 72 + vk0] = w;   // banks 0,2,..,30: ~2-way, free
            }
        }
        __syncthreads();
        if (j0 + 64 < 1024) {                              // register prefetch of next tile
            if (half) {
                const unsigned short* kp = kbase + (size_t)(j0 + 64 + skey) * 512 + sd;
                kr0 = *(const u16x8*)kp; kr1 = *(const u16x8*)(kp + 8);
            } else {
                const unsigned short* vp = vbase + (size_t)(j0 + 64 + vk0) * 512 + vd0;
#pragma unroll
                for (int j = 0; j < 4; ++j) vr[j] = *(const u16x4*)(vp + (size_t)j * 512);
            }
        }

        // S^T = K Q^T : s[ct] rows = keys ct*16+4g+r, col = q = lr
        f32x4 s[4];
#pragma unroll
        for (int ct = 0; ct < 4; ++ct) {
            bf16x8 ka = *(const bf16x8*)&Ks[(ct * 16 + lr) * 72 + g * 8];
            bf16x8 kc = *(const bf16x8*)&Ks[(ct * 16 + lr) * 72 + 32 + g * 8];
            f32x4 z = {};
            z = MFMA_BF16(ka, aq0, z);
            s[ct] = MFMA_BF16(kc, aq1, z);
        }

        // scale + key-mask + blinding; keys are in-lane
        float rmax = -3.0e38f;
#pragma unroll
        for (int ct = 0; ct < 4; ++ct) {
            f32x4 km4 = *(const f32x4*)&kmask[b * 1024 + j0 + ct * 16 + g * 4];
#pragma unroll
            for (int r = 0; r < 4; ++r) {
                int key = j0 + ct * 16 + g * 4 + r;
                float x = s[ct][r] * 0.125f;
                x = (km4[r] == 1.0f) ? x : NEGBIG;
                x = (key == qg) ? NEGBIG : x;
                s[ct][r] = x;
                rmax = fmaxf(rmax, x);
            }
        }
        rmax = fmaxf(rmax, __shfl_xor(rmax, 16, 64));
        rmax = fmaxf(rmax, __shfl_xor(rmax, 32, 64));

        float mn = fmaxf(m_run, rmax);
        float alpha = __expf(m_run - mn);
        m_run = mn;
        float psum = 0.f;
#pragma unroll
        for (int ct = 0; ct < 4; ++ct) {
            f32x4 p;
#pragma unroll
            for (int r = 0; r < 4; ++r) { p[r] = __expf(s[ct][r] - mn); psum += p[r]; }
            bf16x4 pk = { (__bf16)p[0], (__bf16)p[1], (__bf16)p[2], (__bf16)p[3] };
            *(bf16x4*)&Ps[wave][lr * 72 + ct * 16 + g * 4] = pk;
        }
        psum += __shfl_xor(psum, 16, 64);
        psum += __shfl_xor(psum, 32, 64);
        l_run = l_run * alpha + psum;
#pragma unroll
        for (int dt = 0; dt < 4; ++dt) o[dt] *= alpha;

        // O^T += V^T P^T
        bf16x8 p0 = *(const bf16x8*)&Ps[wave][lr * 72 + g * 8];
        bf16x8 p1 = *(const bf16x8*)&Ps[wave][lr * 72 + 32 + g * 8];
#pragma unroll
        for (int dt = 0; dt < 4; ++dt) {
            bf16x8 va = *(const bf16x8*)&Vts[(dt * 16 + lr) * 72 + g * 8];
            bf16x8 vc = *(const bf16x8*)&Vts[(dt * 16 + lr) * 72 + 32 + g * 8];
            o[dt] = MFMA_BF16(va, p0, o[dt]);
            o[dt] = MFMA_BF16(vc, p1, o[dt]);
        }
    }

    // epilogue: normalize, query-mask, residual
    const float inv_l = 1.0f / l_run;
    const float S = 22.627416997969522f;
#pragma unroll
    for (int dt = 0; dt < 4; ++dt) {
        size_t col = (size_t)h * 64 + dt * 16 + g * 4;
        size_t idx = ((size_t)(b * 1024 + qg)) * 512 + col;
        f32x4 qv = *(const f32x4*)&queries[idx];
        f32x4 pv = *(const f32x4*)&pos[(size_t)qg * 512 + col];
        u16x4 wr;
#pragma unroll
        for (int r = 0; r < 4; ++r)
            wr[r] = f2bf(o[dt][r] * inv_l * qm + qv[r] + pv[r] * S);
        *(u16x4*)&Res[idx] = wr;
    }
}

// ---------------- result mean: out[b,d] += mean_t(result) -----------------------------------
__global__ __launch_bounds__(512) void reduce_mean(
    const unsigned short* __restrict__ res, float* __restrict__ out)
{
    const int b = blockIdx.x;
    const int t0 = blockIdx.y * 64;
    const int d = threadIdx.x;
    float acc = 0.f;
    for (int t = t0; t < t0 + 64; ++t)
        acc += bf2f(res[((size_t)(b * 1024 + t)) * 512 + d]);
    atomicAdd(out + b * 512 + d, acc * (1.0f / 1024.0f));
}

extern "C" void kernel_launch(void* const* d_in, const int* in_sizes, int n_in,
                              void* d_out, int out_size, void* d_ws, size_t ws_size,
                              hipStream_t stream)
{
    (void)in_sizes; (void)n_in; (void)out_size; (void)ws_size;
    const float* queries     = (const float*)d_in[0];
    const float* keys        = (const float*)d_in[1];
    const float* query_masks = (const float*)d_in[2];
    const float* key_masks   = (const float*)d_in[3];
    const float* pos_table   = (const float*)d_in[4];
    const float* W_Query     = (const float*)d_in[5];
    const float* W_key       = (const float*)d_in[6];
    const float* W_Value     = (const float*)d_in[7];
    const float* fw1         = (const float*)d_in[8];
    const float* fw2         = (const float*)d_in[9];
    float* out = (float*)d_out;

    unsigned short* ws = (unsigned short*)d_ws;
    const size_t NE = (size_t)8 * 1024 * 512;
    unsigned short* q_in   = ws;               // -> result after attn
    unsigned short* k_in   = ws + NE;
    unsigned short* qb     = ws + 2 * NE;      // hidden (4*NE) starts here after attn
    unsigned short* kb     = ws + 3 * NE;
    unsigned short* vb     = ws + 4 * NE;
    unsigned short* result = q_in;
    unsigned short* hidden = qb;
    unsigned short* wqt    = ws + 6 * NE;
    unsigned short* wkt    = wqt + 512 * 512;
    unsigned short* wvt    = wkt + 512 * 512;
    unsigned short* fw1t   = wvt + 512 * 512;     // 2048 x 512
    unsigned short* fw2t   = fw1t + 2048 * 512;   // 512 x 2048
    unsigned short* wkp    = fw2t + 2048 * 512;   // bf16(W_key), plain
    unsigned short* wkvt   = wkp + 512 * 512;     // (Wk*Wv)^T

    hipMemsetAsync(d_out, 0, 8 * 512 * sizeof(float), stream);
    prep_kernel<<<4096, 256, 0, stream>>>(queries, keys, pos_table, q_in, k_in);
    wconv_kernel<<<2816, 256, 0, stream>>>(W_Query, W_key, W_Value, fw1, fw2,
                                           wqt, wkt, wvt, fw1t, fw2t, wkp);
    gemm_bt<<<dim3(4, 4), 256, 0, stream>>>(wvt, wkp, wkvt, 512, 512, 0);
    proj3_kernel<<<dim3(64, 4, 3), 256, 0, stream>>>(q_in, k_in, wqt, wkt, wkvt, qb, kb, vb);
    attn_kernel<<<dim3(8, 64), 512, 0, stream>>>(qb, kb, vb, queries, pos_table,
                                                 key_masks, query_masks, result);
    reduce_mean<<<dim3(8, 16), 512, 0, stream>>>(result, out);
    gemm_bt<<<dim3(64, 16), 256, 0, stream>>>(result, fw1t, hidden, 2048, 512, 1);
    ffn2_meank<<<dim3(64, 4, 4), 256, 0, stream>>>(hidden, fw2t, out);
}